// Round 1
// baseline (1045.370 us; speedup 1.0000x reference)
//
#include <hip/hip_runtime.h>

#define TT 2048
#define HH 32
#define BB 512

__device__ __forceinline__ float fast_tanh(float x) {
    // tanh(x) = 1 - 2/(exp(2x)+1), exact for all signs; v_exp + v_rcp
    float e = __expf(2.0f * x);
    float r = __builtin_amdgcn_rcpf(e + 1.0f);
    return fmaf(-2.0f, r, 1.0f);
}

__global__ __launch_bounds__(64, 1) void rnn_fused(
    const float* __restrict__ x,      // [B, T, 1]
    const float* __restrict__ hid,    // [2, B, H]
    const float* __restrict__ W_ih0,  // [H, 1]
    const float* __restrict__ W_hh0,  // [H, H]
    const float* __restrict__ b_ih0,  // [H]
    const float* __restrict__ b_hh0,  // [H]
    const float* __restrict__ W_ih1,  // [H, H]
    const float* __restrict__ W_hh1,  // [H, H]
    const float* __restrict__ b_ih1,  // [H]
    const float* __restrict__ b_hh1,  // [H]
    const float* __restrict__ W_fc,   // [1, H]
    const float* __restrict__ b_fc,   // [1]
    float* __restrict__ out)          // [B*T] outs ++ [2*B*H] hidden
{
    const int lane = (int)threadIdx.x;   // 0..63
    const int half = lane >> 5;          // which batch of this wave
    const int i    = lane & 31;          // hidden unit owned by this lane
    const int b    = (int)blockIdx.x * 2 + half;

    __shared__ __align__(16) float h0s[2][HH];
    __shared__ __align__(16) float h1s[2][HH];
    __shared__ __align__(16) float xs[2][32];

    // --- static per-lane state: weight row i of each matrix, in registers ---
    float w0[HH], w1[HH], w2[HH];
#pragma unroll
    for (int j = 0; j < HH; j += 4) {
        float4 a = *(const float4*)(W_hh0 + i * HH + j);
        w0[j] = a.x; w0[j + 1] = a.y; w0[j + 2] = a.z; w0[j + 3] = a.w;
        float4 c = *(const float4*)(W_ih1 + i * HH + j);
        w1[j] = c.x; w1[j + 1] = c.y; w1[j + 2] = c.z; w1[j + 3] = c.w;
        float4 d = *(const float4*)(W_hh1 + i * HH + j);
        w2[j] = d.x; w2[j + 1] = d.y; w2[j + 2] = d.z; w2[j + 3] = d.w;
    }
    const float wx    = W_ih0[i];
    const float bias0 = b_ih0[i] + b_hh0[i];
    const float bias1 = b_ih1[i] + b_hh1[i];
    const float wfc   = W_fc[i];
    const float bfc   = b_fc[0];

    // --- initial hidden state: full vectors per lane ---
    float h0[HH], h1[HH];
#pragma unroll
    for (int j = 0; j < HH; j += 4) {
        float4 a = *(const float4*)(hid + b * HH + j);
        h0[j] = a.x; h0[j + 1] = a.y; h0[j + 2] = a.z; h0[j + 3] = a.w;
        float4 c = *(const float4*)(hid + BB * HH + b * HH + j);
        h1[j] = c.x; h1[j + 1] = c.y; h1[j + 2] = c.z; h1[j + 3] = c.w;
    }

    const float* xrow = x + b * TT;
    float* orow = out + b * TT;

    float h0n = 0.f, h1n = 0.f;

    for (int t = 0; t < TT; ++t) {
        // refill 32 timesteps of x, coalesced (wave-synchronous, no barrier)
        if ((t & 31) == 0) {
            xs[half][i] = xrow[t + i];
        }
        float xv = xs[half][t & 31];

        // ---- layer 0: h0n = tanh(wx*x + b0 + W_hh0 . h0_old) ----
        float a0 = bias0, a1 = 0.f, a2 = 0.f, a3 = 0.f;
#pragma unroll
        for (int j = 0; j < HH; j += 4) {
            a0 = fmaf(w0[j + 0], h0[j + 0], a0);
            a1 = fmaf(w0[j + 1], h0[j + 1], a1);
            a2 = fmaf(w0[j + 2], h0[j + 2], a2);
            a3 = fmaf(w0[j + 3], h0[j + 3], a3);
        }
        float s0 = (a0 + a1) + (a2 + a3);
        s0 = fmaf(wx, xv, s0);
        h0n = fast_tanh(s0);
        h0s[half][i] = h0n;

        // ---- layer 1 recurrent half (uses old h1, overlaps the LDS round-trip) ----
        float c0 = bias1, c1 = 0.f, c2 = 0.f, c3 = 0.f;
#pragma unroll
        for (int j = 0; j < HH; j += 4) {
            c0 = fmaf(w2[j + 0], h1[j + 0], c0);
            c1 = fmaf(w2[j + 1], h1[j + 1], c1);
            c2 = fmaf(w2[j + 2], h1[j + 2], c2);
            c3 = fmaf(w2[j + 3], h1[j + 3], c3);
        }

        // read back full new h0 (broadcast ds_read_b128, conflict-free)
#pragma unroll
        for (int j = 0; j < HH; j += 4) {
            float4 v = *(const float4*)&h0s[half][j];
            h0[j] = v.x; h0[j + 1] = v.y; h0[j + 2] = v.z; h0[j + 3] = v.w;
        }

        // ---- layer 1 input half: += W_ih1 . h0_new ----
#pragma unroll
        for (int j = 0; j < HH; j += 4) {
            c0 = fmaf(w1[j + 0], h0[j + 0], c0);
            c1 = fmaf(w1[j + 1], h0[j + 1], c1);
            c2 = fmaf(w1[j + 2], h0[j + 2], c2);
            c3 = fmaf(w1[j + 3], h0[j + 3], c3);
        }
        float s1 = (c0 + c1) + (c2 + c3);
        h1n = fast_tanh(s1);
        h1s[half][i] = h1n;

        // ---- output projection: butterfly reduce within the 32-lane half ----
        float v = wfc * h1n;
        v += __shfl_xor(v, 1);
        v += __shfl_xor(v, 2);
        v += __shfl_xor(v, 4);
        v += __shfl_xor(v, 8);
        v += __shfl_xor(v, 16);
        if (i == 0) orow[t] = v + bfc;

        // read back full new h1 for next step's recurrent dot
#pragma unroll
        for (int j = 0; j < HH; j += 4) {
            float4 u = *(const float4*)&h1s[half][j];
            h1[j] = u.x; h1[j + 1] = u.y; h1[j + 2] = u.z; h1[j + 3] = u.w;
        }
    }

    // final hidden state [2, B, H]
    out[BB * TT + b * HH + i]           = h0n;
    out[BB * TT + BB * HH + b * HH + i] = h1n;
}

extern "C" void kernel_launch(void* const* d_in, const int* in_sizes, int n_in,
                              void* d_out, int out_size, void* d_ws, size_t ws_size,
                              hipStream_t stream) {
    const float* xp    = (const float*)d_in[0];
    const float* hid   = (const float*)d_in[1];
    const float* Wih0  = (const float*)d_in[2];
    const float* Whh0  = (const float*)d_in[3];
    const float* bih0  = (const float*)d_in[4];
    const float* bhh0  = (const float*)d_in[5];
    const float* Wih1  = (const float*)d_in[6];
    const float* Whh1  = (const float*)d_in[7];
    const float* bih1  = (const float*)d_in[8];
    const float* bhh1  = (const float*)d_in[9];
    const float* Wfc   = (const float*)d_in[10];
    const float* bfc   = (const float*)d_in[11];
    float* outp        = (float*)d_out;

    rnn_fused<<<BB / 2, 64, 0, stream>>>(xp, hid, Wih0, Whh0, bih0, bhh0,
                                         Wih1, Whh1, bih1, bhh1, Wfc, bfc, outp);
}

// Round 2
// 748.381 us; speedup vs baseline: 1.3968x; 1.3968x over previous
//
#include <hip/hip_runtime.h>

#define TT 2048
#define HH 32
#define BB 512

__device__ __forceinline__ float fast_tanh(float x) {
    // tanh(x) = 1 - 2/(exp(2x)+1); v_exp + v_rcp, fp32-accurate enough (~1e-6)
    float e = __expf(2.0f * x);
    float r = __builtin_amdgcn_rcpf(e + 1.0f);
    return fmaf(-2.0f, r, 1.0f);
}

__global__ __launch_bounds__(64, 1) void rnn_fused(
    const float* __restrict__ x,      // [B, T, 1]
    const float* __restrict__ hid,    // [2, B, H]
    const float* __restrict__ W_ih0,  // [H, 1]
    const float* __restrict__ W_hh0,  // [H, H]
    const float* __restrict__ b_ih0,  // [H]
    const float* __restrict__ b_hh0,  // [H]
    const float* __restrict__ W_ih1,  // [H, H]
    const float* __restrict__ W_hh1,  // [H, H]
    const float* __restrict__ b_ih1,  // [H]
    const float* __restrict__ b_hh1,  // [H]
    const float* __restrict__ W_fc,   // [1, H]
    const float* __restrict__ b_fc,   // [1]
    float* __restrict__ out)          // [B*T] outs ++ [2*B*H] hidden
{
    const int lane = (int)threadIdx.x;   // 0..63
    const int half = lane >> 5;          // which batch of this wave
    const int i    = lane & 31;          // hidden unit owned by this lane
    const int b    = (int)blockIdx.x * 2 + half;

    __shared__ __align__(16) float h0s[2][HH];
    __shared__ __align__(16) float h1s[2][HH];
    __shared__ __align__(16) float xs[2][32];
    __shared__ float ring[2][32][33];    // [half][t&31][unit], pad 33 -> conflict-free

    // --- per-lane weight rows in registers ---
    float w0[HH], w1[HH], w2[HH];
#pragma unroll
    for (int j = 0; j < HH; j += 4) {
        float4 a = *(const float4*)(W_hh0 + i * HH + j);
        w0[j] = a.x; w0[j + 1] = a.y; w0[j + 2] = a.z; w0[j + 3] = a.w;
        float4 c = *(const float4*)(W_ih1 + i * HH + j);
        w1[j] = c.x; w1[j + 1] = c.y; w1[j + 2] = c.z; w1[j + 3] = c.w;
        float4 d = *(const float4*)(W_hh1 + i * HH + j);
        w2[j] = d.x; w2[j + 1] = d.y; w2[j + 2] = d.z; w2[j + 3] = d.w;
    }
    const float wx    = W_ih0[i];
    const float bias0 = b_ih0[i] + b_hh0[i];
    const float bias1 = b_ih1[i] + b_hh1[i];
    const float bfc   = b_fc[0];

    // --- initial hidden: full vectors per lane ---
    float H0[HH], H1[HH];
#pragma unroll
    for (int j = 0; j < HH; j += 4) {
        float4 a = *(const float4*)(hid + b * HH + j);
        H0[j] = a.x; H0[j + 1] = a.y; H0[j + 2] = a.z; H0[j + 3] = a.w;
        float4 c = *(const float4*)(hid + BB * HH + b * HH + j);
        H1[j] = c.x; H1[j + 1] = c.y; H1[j + 2] = c.z; H1[j + 3] = c.w;
    }

    const float* xrow = x + b * TT;
    float* orow = out + b * TT;

    // --- x staging: block 0 in LDS, block 1 prefetched in a register ---
    float xcur = xrow[i];
    xs[half][i] = xcur;
    xcur = xrow[32 + i];
    float xv = xs[half][0];

    float h0n = 0.f, h1n = 0.f;

    // ================= t = 0 : layer-0 only =================
    {
        float a0 = bias0, a1 = 0.f, a2 = 0.f, a3 = 0.f;
#pragma unroll
        for (int j = 0; j < HH; j += 4) {
            a0 = fmaf(w0[j + 0], H0[j + 0], a0);
            a1 = fmaf(w0[j + 1], H0[j + 1], a1);
            a2 = fmaf(w0[j + 2], H0[j + 2], a2);
            a3 = fmaf(w0[j + 3], H0[j + 3], a3);
        }
        float s0 = fmaf(wx, xv, (a0 + a1) + (a2 + a3));
        h0n = fast_tanh(s0);
        h0s[half][i] = h0n;
#pragma unroll
        for (int j = 0; j < HH; j += 4) {
            float4 v = *(const float4*)&h0s[half][j];
            H0[j] = v.x; H0[j + 1] = v.y; H0[j + 2] = v.z; H0[j + 3] = v.w;
        }
        xv = xs[half][1];
    }

    // ============ main loop: iter t computes h0[t] and h1[t-1] ============
    for (int t = 1; t < TT; ++t) {
        // layer 0: h0[t] = tanh(wx*x[t] + b0 + W_hh0 . h0[t-1])
        float a0 = bias0, a1 = 0.f, a2 = 0.f, a3 = 0.f;
        // layer 1: h1[t-1] = tanh(b1 + W_ih1 . h0[t-1] + W_hh1 . h1[t-2])
        float c0 = bias1, c1 = 0.f, c2 = 0.f, c3 = 0.f;
#pragma unroll
        for (int j = 0; j < HH; j += 4) {
            a0 = fmaf(w0[j + 0], H0[j + 0], a0);
            a1 = fmaf(w0[j + 1], H0[j + 1], a1);
            a2 = fmaf(w0[j + 2], H0[j + 2], a2);
            a3 = fmaf(w0[j + 3], H0[j + 3], a3);
            c0 = fmaf(w1[j + 0], H0[j + 0], c0);
            c1 = fmaf(w1[j + 1], H0[j + 1], c1);
            c2 = fmaf(w1[j + 2], H0[j + 2], c2);
            c3 = fmaf(w1[j + 3], H0[j + 3], c3);
            c0 = fmaf(w2[j + 0], H1[j + 0], c0);
            c1 = fmaf(w2[j + 1], H1[j + 1], c1);
            c2 = fmaf(w2[j + 2], H1[j + 2], c2);
            c3 = fmaf(w2[j + 3], H1[j + 3], c3);
        }
        float s0 = fmaf(wx, xv, (a0 + a1) + (a2 + a3));
        float s1 = (c0 + c1) + (c2 + c3);
        h0n = fast_tanh(s0);
        h1n = fast_tanh(s1);
        h0s[half][i] = h0n;
        h1s[half][i] = h1n;
        ring[half][(t - 1) & 31][i] = h1n;

        // fc flush: every 32 steps, lane k computes out[t-32+k] privately
        if ((t & 31) == 0) {
            float f0 = bfc, f1 = 0.f, f2 = 0.f, f3 = 0.f;
#pragma unroll
            for (int j = 0; j < HH; j += 4) {
                f0 = fmaf(W_fc[j + 0], ring[half][i][j + 0], f0);
                f1 = fmaf(W_fc[j + 1], ring[half][i][j + 1], f1);
                f2 = fmaf(W_fc[j + 2], ring[half][i][j + 2], f2);
                f3 = fmaf(W_fc[j + 3], ring[half][i][j + 3], f3);
            }
            orow[t - 32 + i] = (f0 + f1) + (f2 + f3);
        }

        // single readback phase: H0 <- h0[t], H1 <- h1[t-1]
#pragma unroll
        for (int j = 0; j < HH; j += 4) {
            float4 v = *(const float4*)&h0s[half][j];
            H0[j] = v.x; H0[j + 1] = v.y; H0[j + 2] = v.z; H0[j + 3] = v.w;
            float4 u = *(const float4*)&h1s[half][j];
            H1[j] = u.x; H1[j + 1] = u.y; H1[j + 2] = u.z; H1[j + 3] = u.w;
        }

        // x handling for t+1 (global prefetch 32 steps ahead, xv 1 step ahead)
        int tn = t + 1;
        if (tn < TT) {
            if ((tn & 31) == 0) {
                xs[half][i] = xcur;
                int idx = tn + 32 + i;
                idx = idx < TT ? idx : TT - 1;
                xcur = xrow[idx];
            }
            xv = xs[half][tn & 31];
        }
    }

    // ================= t = TT : layer-1 tail + final flush =================
    {
        float c0 = bias1, c1 = 0.f, c2 = 0.f, c3 = 0.f;
#pragma unroll
        for (int j = 0; j < HH; j += 4) {
            c0 = fmaf(w1[j + 0], H0[j + 0], c0);
            c1 = fmaf(w1[j + 1], H0[j + 1], c1);
            c2 = fmaf(w1[j + 2], H0[j + 2], c2);
            c3 = fmaf(w2[j + 0], H1[j + 0], c0) - c0 + c3;  // keep simple: see below
        }
        // redo cleanly to avoid cleverness:
        c0 = bias1; c1 = 0.f; c2 = 0.f; c3 = 0.f;
#pragma unroll
        for (int j = 0; j < HH; j += 4) {
            c0 = fmaf(w1[j + 0], H0[j + 0], c0);
            c1 = fmaf(w1[j + 1], H0[j + 1], c1);
            c2 = fmaf(w1[j + 2], H0[j + 2], c2);
            c3 = fmaf(w1[j + 3], H0[j + 3], c3);
            c0 = fmaf(w2[j + 0], H1[j + 0], c0);
            c1 = fmaf(w2[j + 1], H1[j + 1], c1);
            c2 = fmaf(w2[j + 2], H1[j + 2], c2);
            c3 = fmaf(w2[j + 3], H1[j + 3], c3);
        }
        h1n = fast_tanh((c0 + c1) + (c2 + c3));
        ring[half][31][i] = h1n;   // (TT-1) & 31 == 31

        float f0 = bfc, f1 = 0.f, f2 = 0.f, f3 = 0.f;
#pragma unroll
        for (int j = 0; j < HH; j += 4) {
            f0 = fmaf(W_fc[j + 0], ring[half][i][j + 0], f0);
            f1 = fmaf(W_fc[j + 1], ring[half][i][j + 1], f1);
            f2 = fmaf(W_fc[j + 2], ring[half][i][j + 2], f2);
            f3 = fmaf(W_fc[j + 3], ring[half][i][j + 3], f3);
        }
        orow[TT - 32 + i] = (f0 + f1) + (f2 + f3);
    }

    // final hidden state [2, B, H]: h0[TT-1] (from last main iter), h1[TT-1]
    out[BB * TT + b * HH + i]           = h0n;
    out[BB * TT + BB * HH + b * HH + i] = h1n;
}

extern "C" void kernel_launch(void* const* d_in, const int* in_sizes, int n_in,
                              void* d_out, int out_size, void* d_ws, size_t ws_size,
                              hipStream_t stream) {
    const float* xp    = (const float*)d_in[0];
    const float* hid   = (const float*)d_in[1];
    const float* Wih0  = (const float*)d_in[2];
    const float* Whh0  = (const float*)d_in[3];
    const float* bih0  = (const float*)d_in[4];
    const float* bhh0  = (const float*)d_in[5];
    const float* Wih1  = (const float*)d_in[6];
    const float* Whh1  = (const float*)d_in[7];
    const float* bih1  = (const float*)d_in[8];
    const float* bhh1  = (const float*)d_in[9];
    const float* Wfc   = (const float*)d_in[10];
    const float* bfc   = (const float*)d_in[11];
    float* outp        = (float*)d_out;

    rnn_fused<<<BB / 2, 64, 0, stream>>>(xp, hid, Wih0, Whh0, bih0, bhh0,
                                         Wih1, Whh1, bih1, bhh1, Wfc, bfc, outp);
}

// Round 3
// 460.937 us; speedup vs baseline: 2.2679x; 1.6236x over previous
//
#include <hip/hip_runtime.h>

#define TT 2048
#define HH 32
#define BB 512

typedef float f32x2 __attribute__((ext_vector_type(2)));
typedef float f32x4 __attribute__((ext_vector_type(4)));

// packed fp32 fma: acc = a*b + acc (elementwise on a VGPR pair)
#define PKFMA(acc, a, b) asm("v_pk_fma_f32 %0, %1, %2, %0" : "+v"(acc) : "v"(a), "v"(b))

__device__ __forceinline__ float tanh_pre(float s2) {
    // input is ALREADY 2x (folded into weights): tanh(x) = 1 - 2/(exp(2x)+1)
    float e = __expf(s2);
    float r = __builtin_amdgcn_rcpf(e + 1.0f);
    return fmaf(-2.0f, r, 1.0f);
}

__global__ __launch_bounds__(64, 1) void rnn_fused(
    const float* __restrict__ x,      // [B, T, 1]
    const float* __restrict__ hid,    // [2, B, H]
    const float* __restrict__ W_ih0,  // [H, 1]
    const float* __restrict__ W_hh0,  // [H, H]
    const float* __restrict__ b_ih0,  // [H]
    const float* __restrict__ b_hh0,  // [H]
    const float* __restrict__ W_ih1,  // [H, H]
    const float* __restrict__ W_hh1,  // [H, H]
    const float* __restrict__ b_ih1,  // [H]
    const float* __restrict__ b_hh1,  // [H]
    const float* __restrict__ W_fc,   // [1, H]
    const float* __restrict__ b_fc,   // [1]
    float* __restrict__ out)          // [B*T] outs ++ [2*B*H] hidden
{
    const int lane = (int)threadIdx.x;
    const int half = lane >> 5;
    const int i    = lane & 31;
    const int b    = (int)blockIdx.x * 2 + half;

    __shared__ __align__(16) float h0s[2][HH];
    __shared__ __align__(16) float h1s[2][HH];
    __shared__ __align__(16) float xs[2][32];
    __shared__ float ring[2][32][33];   // pad 33 -> conflict-free row reads

    // --- weight rows (scaled by 2 for the tanh fold; exact pow-2) ---
    f32x2 w0p[16], w1p[16], w2p[16];
#pragma unroll
    for (int j = 0; j < 8; ++j) {
        f32x4 a = *(const f32x4*)(W_hh0 + i * HH + 4 * j) * 2.0f;
        w0p[2 * j]     = __builtin_shufflevector(a, a, 0, 1);
        w0p[2 * j + 1] = __builtin_shufflevector(a, a, 2, 3);
        f32x4 c = *(const f32x4*)(W_ih1 + i * HH + 4 * j) * 2.0f;
        w1p[2 * j]     = __builtin_shufflevector(c, c, 0, 1);
        w1p[2 * j + 1] = __builtin_shufflevector(c, c, 2, 3);
        f32x4 d = *(const f32x4*)(W_hh1 + i * HH + 4 * j) * 2.0f;
        w2p[2 * j]     = __builtin_shufflevector(d, d, 0, 1);
        w2p[2 * j + 1] = __builtin_shufflevector(d, d, 2, 3);
    }
    const float wxs    = 2.0f * W_ih0[i];
    const float bias0s = 2.0f * (b_ih0[i] + b_hh0[i]);
    const float bias1s = 2.0f * (b_ih1[i] + b_hh1[i]);
    const float bfc    = b_fc[0];

    float wf[32];   // uniform -> SGPRs
#pragma unroll
    for (int j = 0; j < 32; ++j) wf[j] = W_fc[j];

    // --- initial hidden (unscaled) ---
    f32x2 H0p[16], H1p[16];
#pragma unroll
    for (int j = 0; j < 8; ++j) {
        f32x4 a = *(const f32x4*)(hid + b * HH + 4 * j);
        H0p[2 * j]     = __builtin_shufflevector(a, a, 0, 1);
        H0p[2 * j + 1] = __builtin_shufflevector(a, a, 2, 3);
        f32x4 c = *(const f32x4*)(hid + BB * HH + b * HH + 4 * j);
        H1p[2 * j]     = __builtin_shufflevector(c, c, 0, 1);
        H1p[2 * j + 1] = __builtin_shufflevector(c, c, 2, 3);
    }

    const float* xrow = x + b * TT;
    float* orow = out + b * TT;

    xs[half][i] = xrow[i];
    float xcur = xrow[32 + i];

    float h0n = 0.f, h1n = 0.f;

    // iter t computes h0[t] and h1[t-1]; H0p=h0[t-1], H1p=h1[t-2] on entry
    for (int tb = 0; tb < 64; ++tb) {
        const int base = tb * 32;
#pragma unroll
        for (int k = 0; k < 32; ++k) {            // t = base + k; k is compile-time
            float xv = xs[half][k];

            // ---- layer 0 ----
            f32x2 A0 = {bias0s, 0.f}, A1 = {0.f, 0.f};
#pragma unroll
            for (int j = 0; j < 16; j += 2) {
                PKFMA(A0, w0p[j],     H0p[j]);
                PKFMA(A1, w0p[j + 1], H0p[j + 1]);
            }
            f32x2 As = A0 + A1;
            h0n = tanh_pre(fmaf(wxs, xv, As.x + As.y));
            h0s[half][i] = h0n;

            // ---- layer 1 (skipped only at t==0) ----
            if (k != 0 || tb != 0) {
                f32x2 C0 = {bias1s, 0.f}, C1 = {0.f, 0.f}, C2 = {0.f, 0.f}, C3 = {0.f, 0.f};
#pragma unroll
                for (int j = 0; j < 16; j += 2) {
                    PKFMA(C0, w1p[j],     H0p[j]);
                    PKFMA(C1, w1p[j + 1], H0p[j + 1]);
                    PKFMA(C2, w2p[j],     H1p[j]);
                    PKFMA(C3, w2p[j + 1], H1p[j + 1]);
                }
                f32x2 Cs = (C0 + C1) + (C2 + C3);
                h1n = tanh_pre(Cs.x + Cs.y);
                h1s[half][i] = h1n;
                ring[half][(k + 31) & 31][i] = h1n;   // slot (t-1)&31, static offset
            }

            // ---- fc flush: once per 32 steps, static slot reads, row i pad-33 ----
            if (k == 0) {
                if (tb != 0) {
                    float f0 = bfc, f1 = 0.f, f2 = 0.f, f3 = 0.f;
#pragma unroll
                    for (int j = 0; j < 32; j += 4) {
                        f0 = fmaf(wf[j],     ring[half][i][j],     f0);
                        f1 = fmaf(wf[j + 1], ring[half][i][j + 1], f1);
                        f2 = fmaf(wf[j + 2], ring[half][i][j + 2], f2);
                        f3 = fmaf(wf[j + 3], ring[half][i][j + 3], f3);
                    }
                    orow[base - 32 + i] = (f0 + f1) + (f2 + f3);
                }
            }

            // ---- readback: H0p <- h0[t]; H1p <- h1[t-1] ----
#pragma unroll
            for (int j = 0; j < 8; ++j) {
                f32x4 v = *(const f32x4*)&h0s[half][4 * j];
                H0p[2 * j]     = __builtin_shufflevector(v, v, 0, 1);
                H0p[2 * j + 1] = __builtin_shufflevector(v, v, 2, 3);
            }
            if (k != 0 || tb != 0) {
#pragma unroll
                for (int j = 0; j < 8; ++j) {
                    f32x4 u = *(const f32x4*)&h1s[half][4 * j];
                    H1p[2 * j]     = __builtin_shufflevector(u, u, 0, 1);
                    H1p[2 * j + 1] = __builtin_shufflevector(u, u, 2, 3);
                }
            }

            // ---- x restage for next 32-block (prefetched 32 ahead) ----
            if (k == 31) {
                xs[half][i] = xcur;
                int idx = base + 64 + i;
                if (idx >= TT) idx = TT - 1;
                xcur = xrow[idx];
            }
        }
    }

    // ---- epilogue t=TT: h1[TT-1] + final flush ----
    {
        f32x2 C0 = {bias1s, 0.f}, C1 = {0.f, 0.f}, C2 = {0.f, 0.f}, C3 = {0.f, 0.f};
#pragma unroll
        for (int j = 0; j < 16; j += 2) {
            PKFMA(C0, w1p[j],     H0p[j]);
            PKFMA(C1, w1p[j + 1], H0p[j + 1]);
            PKFMA(C2, w2p[j],     H1p[j]);
            PKFMA(C3, w2p[j + 1], H1p[j + 1]);
        }
        f32x2 Cs = (C0 + C1) + (C2 + C3);
        h1n = tanh_pre(Cs.x + Cs.y);
        ring[half][31][i] = h1n;

        float f0 = bfc, f1 = 0.f, f2 = 0.f, f3 = 0.f;
#pragma unroll
        for (int j = 0; j < 32; j += 4) {
            f0 = fmaf(wf[j],     ring[half][i][j],     f0);
            f1 = fmaf(wf[j + 1], ring[half][i][j + 1], f1);
            f2 = fmaf(wf[j + 2], ring[half][i][j + 2], f2);
            f3 = fmaf(wf[j + 3], ring[half][i][j + 3], f3);
        }
        orow[TT - 32 + i] = (f0 + f1) + (f2 + f3);
    }

    // final hidden [2, B, H]
    out[BB * TT + b * HH + i]           = h0n;
    out[BB * TT + BB * HH + b * HH + i] = h1n;
}

extern "C" void kernel_launch(void* const* d_in, const int* in_sizes, int n_in,
                              void* d_out, int out_size, void* d_ws, size_t ws_size,
                              hipStream_t stream) {
    const float* xp    = (const float*)d_in[0];
    const float* hid   = (const float*)d_in[1];
    const float* Wih0  = (const float*)d_in[2];
    const float* Whh0  = (const float*)d_in[3];
    const float* bih0  = (const float*)d_in[4];
    const float* bhh0  = (const float*)d_in[5];
    const float* Wih1  = (const float*)d_in[6];
    const float* Whh1  = (const float*)d_in[7];
    const float* bih1  = (const float*)d_in[8];
    const float* bhh1  = (const float*)d_in[9];
    const float* Wfc   = (const float*)d_in[10];
    const float* bfc   = (const float*)d_in[11];
    float* outp        = (float*)d_out;

    rnn_fused<<<BB / 2, 64, 0, stream>>>(xp, hid, Wih0, Whh0, bih0, bhh0,
                                         Wih1, Whh1, bih1, bhh1, Wfc, bfc, outp);
}